// Round 1
// baseline (2082.046 us; speedup 1.0000x reference)
//
#include <hip/hip_runtime.h>

// ---------- types / helpers ----------
typedef __attribute__((ext_vector_type(8))) short short8;   // 8 x bf16 bits
typedef __attribute__((ext_vector_type(4))) float float4v;
typedef __attribute__((ext_vector_type(4))) unsigned short u16x4;

__device__ __forceinline__ float bf2f(unsigned short u) {
    union { unsigned int i; float f; } v; v.i = ((unsigned int)u) << 16; return v.f;
}
__device__ __forceinline__ unsigned short f2bf(float f) {   // round-to-nearest-even
    union { float f; unsigned int u; } v; v.f = f;
    unsigned int u = v.u;
    return (unsigned short)((u + 0x7fffu + ((u >> 16) & 1u)) >> 16);
}
__device__ __forceinline__ void load_lds16(const void* g, void* l) {
    __builtin_amdgcn_global_load_lds((const __attribute__((address_space(1))) void*)g,
                                     (__attribute__((address_space(3))) void*)l, 16, 0, 0);
}
__device__ __forceinline__ float wred(float v) {
#pragma unroll
    for (int o = 32; o > 0; o >>= 1) v += __shfl_down(v, o);
    return __shfl(v, 0);
}

// ---------- problem dims ----------
#define BB 8192
#define DD 1024
#define HH 2048
#define HM 1024
#define CC 1000
#define CP 1024
#define EE 8
#define CAP 17408           // 136 row tiles of 128
#define NT_CAP 136

// ---------- ws layout (bytes) ----------
#define OFF_XHI   0ull
#define OFF_XLO   16777216ull
#define OFF_W1TH  33554432ull
#define OFF_W1TL  37748736ull
#define OFF_W2T   41943040ull
#define OFF_HPH   50331648ull   // ends 83886080
#define OFF_GF    0ull          // alias: x/fw1T/fw2T/hpre_hi (dead after L2/pk)
#define OFF_HPL   83886080ull   // ends 117440512
#define OFF_M2    117440512ull
#define OFF_B2    118489088ull
#define OFF_FEATS 118490112ull  // bf16 feats, ends 152044544
#define OFF_PK    152044544ull  // ends 156238848
#define OFF_H1    83886080ull   // alias: hpre_lo/M2/feats/pk (dead after gather)
#define OFF_EW1T  156238848ull  // ends 223347712
#define OFF_H2    156238848ull  // alias ew1T (dead after expert L1)
#define OFF_EW2T  223347712ull
#define OFF_EW3T  256902144ull
#define OFF_WSLOT 273679360ull
#define OFF_ROWSL 273748992ull
#define OFF_TOPE  273818624ull
#define OFF_TOPW  273884160ull
#define OFF_CNT   273949696ull

// ---------- conversion kernels ----------
__global__ __launch_bounds__(256) void k_split_convert(const float* __restrict__ in,
    unsigned short* __restrict__ hi, unsigned short* __restrict__ lo, int n)
{
    int i = (blockIdx.x * 256 + threadIdx.x) * 4;
    if (i >= n) return;
    float4 v = *(const float4*)(in + i);
    unsigned short h0 = f2bf(v.x), h1 = f2bf(v.y), h2 = f2bf(v.z), h3 = f2bf(v.w);
    u16x4 hv = {h0, h1, h2, h3};
    u16x4 lv = {f2bf(v.x - bf2f(h0)), f2bf(v.y - bf2f(h1)),
                f2bf(v.z - bf2f(h2)), f2bf(v.w - bf2f(h3))};
    *(u16x4*)(hi + i) = hv;
    *(u16x4*)(lo + i) = lv;
}

// out[b][n][k] = in[b][k][n]  (bf16, zero-pad n >= N up to Npad)
template<bool SPLIT>
__global__ __launch_bounds__(256) void k_transpose(const float* __restrict__ in,
    unsigned short* __restrict__ hi, unsigned short* __restrict__ lo, int K, int N, int Npad)
{
    __shared__ float tile[32][33];
    const float* src = in + (size_t)blockIdx.z * K * N;
    int n0 = blockIdx.x * 32, k0 = blockIdx.y * 32;
    int tx = threadIdx.x & 31, ty = threadIdx.x >> 5;
#pragma unroll
    for (int r = ty; r < 32; r += 8) {
        int n = n0 + tx;
        tile[r][tx] = (n < N) ? src[(size_t)(k0 + r) * N + n] : 0.f;
    }
    __syncthreads();
    size_t ob = (size_t)blockIdx.z * Npad * K;
#pragma unroll
    for (int r = ty; r < 32; r += 8) {
        float v = tile[tx][r];
        size_t o = ob + (size_t)(n0 + r) * K + k0 + tx;
        unsigned short h = f2bf(v);
        hi[o] = h;
        if (SPLIT) lo[o] = f2bf(v - bf2f(h));
    }
}

// ---------- bf16 MFMA GEMM core: C[128,128] tile of A[M,K] @ Bt[N,K]^T ----------
__device__ __forceinline__ void gemm_core(const unsigned short* __restrict__ A,
    const unsigned short* __restrict__ Bt, int K, int row0, int col0,
    unsigned short* As, unsigned short* Bs, float4v (&acc)[4][4])
{
    const int t = threadIdx.x, lane = t & 63, w = t >> 6;
    const int lrow = lane & 15, quad = lane >> 4;
    const int swz = (quad ^ ((lrow >> 1) & 3)) * 8;
    const int wr = (w & 1) * 64, wc = (w >> 1) * 64;
    for (int k0 = 0; k0 < K; k0 += 32) {
#pragma unroll
        for (int p = 0; p < 2; ++p) {
            int c = p * 256 + t;
            int r = c >> 2, q = (c & 3) ^ ((r >> 1) & 3);
            int lo_ = (p * 256 + w * 64) * 8;               // wave-uniform LDS dest
            load_lds16(A + (size_t)(row0 + r) * K + k0 + q * 8, As + lo_);
            load_lds16(Bt + (size_t)(col0 + r) * K + k0 + q * 8, Bs + lo_);
        }
        __syncthreads();
        short8 af[4], bfr[4];
#pragma unroll
        for (int i = 0; i < 4; ++i) af[i]  = *(const short8*)(As + (wr + i * 16 + lrow) * 32 + swz);
#pragma unroll
        for (int j = 0; j < 4; ++j) bfr[j] = *(const short8*)(Bs + (wc + j * 16 + lrow) * 32 + swz);
#pragma unroll
        for (int i = 0; i < 4; ++i)
#pragma unroll
            for (int j = 0; j < 4; ++j)
                acc[i][j] = __builtin_amdgcn_mfma_f32_16x16x32_bf16(af[i], bfr[j], acc[i][j], 0, 0, 0);
        __syncthreads();
    }
}

// ---------- layer 1: split (bf16x2) GEMM, relu, split-store ----------
__global__ __launch_bounds__(256, 2) void k_l1(
    const unsigned short* __restrict__ xh, const unsigned short* __restrict__ xl,
    const unsigned short* __restrict__ wh, const unsigned short* __restrict__ wl,
    const float* __restrict__ bias, unsigned short* __restrict__ oh, unsigned short* __restrict__ ol)
{
    __shared__ __align__(16) unsigned short Ash[4096], Asl[4096], Bsh[4096], Bsl[4096];
    const int K = DD, N = HH;
    const int row0 = blockIdx.x * 128, col0 = blockIdx.y * 128;
    const int t = threadIdx.x, lane = t & 63, w = t >> 6;
    const int lrow = lane & 15, quad = lane >> 4;
    const int swz = (quad ^ ((lrow >> 1) & 3)) * 8;
    const int wr = (w & 1) * 64, wc = (w >> 1) * 64;
    float4v acc[4][4] = {};
    for (int k0 = 0; k0 < K; k0 += 32) {
#pragma unroll
        for (int p = 0; p < 2; ++p) {
            int c = p * 256 + t;
            int r = c >> 2, q = (c & 3) ^ ((r >> 1) & 3);
            size_t ga = (size_t)(row0 + r) * K + k0 + q * 8;
            size_t gb = (size_t)(col0 + r) * K + k0 + q * 8;
            int lo_ = (p * 256 + w * 64) * 8;
            load_lds16(xh + ga, Ash + lo_);
            load_lds16(xl + ga, Asl + lo_);
            load_lds16(wh + gb, Bsh + lo_);
            load_lds16(wl + gb, Bsl + lo_);
        }
        __syncthreads();
        short8 ah[4], al[4], bh[4], bl[4];
#pragma unroll
        for (int i = 0; i < 4; ++i) {
            int o = (wr + i * 16 + lrow) * 32 + swz;
            ah[i] = *(const short8*)(Ash + o);
            al[i] = *(const short8*)(Asl + o);
        }
#pragma unroll
        for (int j = 0; j < 4; ++j) {
            int o = (wc + j * 16 + lrow) * 32 + swz;
            bh[j] = *(const short8*)(Bsh + o);
            bl[j] = *(const short8*)(Bsl + o);
        }
#pragma unroll
        for (int i = 0; i < 4; ++i)
#pragma unroll
            for (int j = 0; j < 4; ++j) {
                float4v a0 = __builtin_amdgcn_mfma_f32_16x16x32_bf16(al[i], bh[j], acc[i][j], 0, 0, 0);
                a0 = __builtin_amdgcn_mfma_f32_16x16x32_bf16(ah[i], bl[j], a0, 0, 0, 0);
                acc[i][j] = __builtin_amdgcn_mfma_f32_16x16x32_bf16(ah[i], bh[j], a0, 0, 0, 0);
            }
        __syncthreads();
    }
#pragma unroll
    for (int i = 0; i < 4; ++i)
#pragma unroll
        for (int r = 0; r < 4; ++r) {
            int row = row0 + wr + i * 16 + quad * 4 + r;
            size_t base = (size_t)row * N;
#pragma unroll
            for (int j = 0; j < 4; ++j) {
                int col = col0 + wc + j * 16 + lrow;
                float v = fmaxf(acc[i][j][r] + bias[col], 0.f);
                unsigned short h = f2bf(v);
                oh[base + col] = h;
                ol[base + col] = f2bf(v - bf2f(h));
            }
        }
}

// ---------- layer 2: single bf16 GEMM -> feats bf16 (no relu) ----------
__global__ __launch_bounds__(256, 2) void k_l2(const unsigned short* __restrict__ A,
    const unsigned short* __restrict__ Bt, const float* __restrict__ bias,
    unsigned short* __restrict__ outb)
{
    __shared__ __align__(16) unsigned short As[4096], Bs[4096];
    const int K = HH, N = HH;
    const int row0 = blockIdx.x * 128, col0 = blockIdx.y * 128;
    float4v acc[4][4] = {};
    gemm_core(A, Bt, K, row0, col0, As, Bs, acc);
    const int lane = threadIdx.x & 63, w = threadIdx.x >> 6;
    const int lrow = lane & 15, quad = lane >> 4;
    const int wr = (w & 1) * 64, wc = (w >> 1) * 64;
#pragma unroll
    for (int i = 0; i < 4; ++i)
#pragma unroll
        for (int r = 0; r < 4; ++r) {
            int row = row0 + wr + i * 16 + quad * 4 + r;
            size_t base = (size_t)row * N;
#pragma unroll
            for (int j = 0; j < 4; ++j) {
                int col = col0 + wc + j * 16 + lrow;
                outb[base + col] = f2bf(acc[i][j][r] + bias[col]);
            }
        }
}

// ---------- expert GEMM (relu, bf16 out), expert chosen per 128-row tile ----------
__global__ __launch_bounds__(256, 2) void k_le(const unsigned short* __restrict__ A,
    const unsigned short* __restrict__ WT, const float* __restrict__ bias,
    unsigned short* __restrict__ out, const int* __restrict__ offs, int N, int K)
{
    __shared__ __align__(16) unsigned short As[4096], Bs[4096];
    const int row0 = blockIdx.x * 128;
    if (row0 >= offs[8]) return;
    int e = 0;
#pragma unroll
    for (int i = 1; i < 8; ++i) if (offs[i] <= row0) e = i;
    const unsigned short* Bt = WT + (size_t)e * N * K;
    const float* bs = bias + (size_t)e * N;
    const int col0 = blockIdx.y * 128;
    float4v acc[4][4] = {};
    gemm_core(A, Bt, K, row0, col0, As, Bs, acc);
    const int lane = threadIdx.x & 63, w = threadIdx.x >> 6;
    const int lrow = lane & 15, quad = lane >> 4;
    const int wr = (w & 1) * 64, wc = (w >> 1) * 64;
#pragma unroll
    for (int i = 0; i < 4; ++i)
#pragma unroll
        for (int r = 0; r < 4; ++r) {
            int row = row0 + wr + i * 16 + quad * 4 + r;
            size_t base = (size_t)row * N;
#pragma unroll
            for (int j = 0; j < 4; ++j) {
                int col = col0 + wc + j * 16 + lrow;
                out[base + col] = f2bf(fmaxf(acc[i][j][r] + bs[col], 0.f));
            }
        }
}

// ---------- final expert GEMM: weighted atomic accumulate into final ----------
__global__ __launch_bounds__(256, 2) void k_final(const unsigned short* __restrict__ A,
    const unsigned short* __restrict__ WT, const float* __restrict__ bias,
    float* __restrict__ outF, const int* __restrict__ offs,
    const int* __restrict__ rowslot, const float* __restrict__ wslot)
{
    __shared__ __align__(16) unsigned short As[4096], Bs[4096];
    const int N = CP, K = HM;
    const int row0 = blockIdx.x * 128;
    if (row0 >= offs[8]) return;
    int e = 0;
#pragma unroll
    for (int i = 1; i < 8; ++i) if (offs[i] <= row0) e = i;
    const unsigned short* Bt = WT + (size_t)e * N * K;
    const float* bs = bias + (size_t)e * CC;
    const int col0 = blockIdx.y * 128;
    float4v acc[4][4] = {};
    gemm_core(A, Bt, K, row0, col0, As, Bs, acc);
    const int lane = threadIdx.x & 63, w = threadIdx.x >> 6;
    const int lrow = lane & 15, quad = lane >> 4;
    const int wr = (w & 1) * 64, wc = (w >> 1) * 64;
#pragma unroll
    for (int i = 0; i < 4; ++i)
#pragma unroll
        for (int r = 0; r < 4; ++r) {
            int row = row0 + wr + i * 16 + quad * 4 + r;
            float wv = wslot[row];
            if (wv != 0.f) {
                float* frow = outF + (size_t)rowslot[row] * CC;
#pragma unroll
                for (int j = 0; j < 4; ++j) {
                    int col = col0 + wc + j * 16 + lrow;
                    if (col < CC) atomicAdd(frow + col, wv * (acc[i][j][r] + bs[col]));
                }
            }
        }
}

// ---------- fp32 vector GEMM  out[M,128] = A[M,KD] @ B[KD,128] (+bias) ----------
template<bool SPLITIN>
__global__ __launch_bounds__(256, 2) void k_pk(const float* __restrict__ A,
    const unsigned short* __restrict__ Ah, const unsigned short* __restrict__ Al,
    const float* __restrict__ Bm, const float* __restrict__ bias,
    float* __restrict__ out, int KD)
{
    __shared__ __align__(16) float As[64 * 32];
    __shared__ __align__(16) float Bs[32 * 128];
    const int t = threadIdx.x;
    const int row0 = blockIdx.x * 64;
    const int tr = t >> 5, tc = t & 31;
    float acc[8][4] = {};
    for (int k0 = 0; k0 < KD; k0 += 32) {
#pragma unroll
        for (int i = 0; i < 8; ++i) {
            int idx = t + i * 256;
            int r = idx >> 5, c = idx & 31;
            size_t g = (size_t)(row0 + r) * KD + k0 + c;
            As[idx] = SPLITIN ? (bf2f(Ah[g]) + bf2f(Al[g])) : A[g];
        }
#pragma unroll
        for (int i = 0; i < 16; ++i) {
            int idx = t + i * 256;
            int r = idx >> 7, c = idx & 127;
            Bs[idx] = Bm[(size_t)(k0 + r) * 128 + c];
        }
        __syncthreads();
#pragma unroll 4
        for (int kk = 0; kk < 32; ++kk) {
            float4 bv = *(const float4*)&Bs[kk * 128 + tc * 4];
#pragma unroll
            for (int r8 = 0; r8 < 8; ++r8) {
                float av = As[(r8 * 8 + tr) * 32 + kk];
                acc[r8][0] += av * bv.x; acc[r8][1] += av * bv.y;
                acc[r8][2] += av * bv.z; acc[r8][3] += av * bv.w;
            }
        }
        __syncthreads();
    }
#pragma unroll
    for (int r8 = 0; r8 < 8; ++r8) {
        size_t row = row0 + r8 * 8 + tr;
#pragma unroll
        for (int c = 0; c < 4; ++c)
            out[row * 128 + tc * 4 + c] = acc[r8][c] + (bias ? bias[tc * 4 + c] : 0.f);
    }
}

__global__ void k_bias2(const float* __restrict__ fb2, const float* __restrict__ kw,
                        const float* __restrict__ kb, float* __restrict__ bias2)
{
    int c = threadIdx.x;
    float s = kb[c];
    for (int j = 0; j < HH; ++j) s += fb2[j] * kw[(size_t)j * 128 + c];
    bias2[c] = s;
}

// ---------- routing ----------
__global__ __launch_bounds__(64) void k_route(const float* __restrict__ pk,
    const float* __restrict__ keys, float* __restrict__ wout, float* __restrict__ tout,
    float* __restrict__ simout, int* __restrict__ top_e, float* __restrict__ top_w,
    int* __restrict__ cnt)
{
    int b = blockIdx.x, lane = threadIdx.x;
    float2 v = *(const float2*)&pk[(size_t)b * 128 + lane * 2];
    float inv = 1.f / fmaxf(sqrtf(wred(v.x * v.x + v.y * v.y)), 1e-12f);
    float sims[8];
#pragma unroll
    for (int e = 0; e < 8; ++e) {
        float2 kv = *(const float2*)&keys[e * 128 + lane * 2];
        float kinv = 1.f / fmaxf(sqrtf(wred(kv.x * kv.x + kv.y * kv.y)), 1e-12f);
        float d = wred(v.x * kv.x + v.y * kv.y);
        sims[e] = d * inv * kinv;
    }
    if (lane == 0) {
        int i1 = 0; float v1 = sims[0];
#pragma unroll
        for (int e = 1; e < 8; ++e) if (sims[e] > v1) { v1 = sims[e]; i1 = e; }
        int i2 = -1; float v2 = -1e30f;
#pragma unroll
        for (int e = 0; e < 8; ++e) if (e != i1 && sims[e] > v2) { v2 = sims[e]; i2 = e; }
        float e2 = expf(v2 - v1);
        float w1 = 1.f / (1.f + e2), w2 = e2 / (1.f + e2);
#pragma unroll
        for (int e = 0; e < 8; ++e) simout[(size_t)b * 8 + e] = sims[e];
        wout[(size_t)b * 8 + i1] = w1;
        wout[(size_t)b * 8 + i2] = w2;
        tout[(size_t)b * 2] = (float)i1; tout[(size_t)b * 2 + 1] = (float)i2;
        top_e[b * 2] = i1; top_e[b * 2 + 1] = i2;
        top_w[b * 2] = w1; top_w[b * 2 + 1] = w2;
        atomicAdd(&cnt[i1], 1); atomicAdd(&cnt[i2], 1);
    }
}

__global__ void k_offs(const int* __restrict__ cnt, int* __restrict__ offs)
{
    if (threadIdx.x == 0) {
        int o = 0;
        for (int e = 0; e < 8; ++e) { offs[e] = o; o += ((cnt[e] + 127) >> 7) << 7; }
        offs[8] = o;
    }
}

__global__ __launch_bounds__(256) void k_scatter(const int* __restrict__ top_e,
    const float* __restrict__ top_w, const int* __restrict__ offs, int* __restrict__ cnt2,
    int* __restrict__ rowslot, float* __restrict__ wslot)
{
    int b = blockIdx.x * 256 + threadIdx.x;
    if (b >= BB) return;
#pragma unroll
    for (int j = 0; j < 2; ++j) {
        int e = top_e[b * 2 + j];
        int idx = atomicAdd(&cnt2[e], 1);
        int s = offs[e] + idx;
        rowslot[s] = b;
        wslot[s] = top_w[b * 2 + j];
    }
}

__global__ __launch_bounds__(256) void k_gather(const unsigned short* __restrict__ featsb,
    const int* __restrict__ offs, const int* __restrict__ cnt, int* __restrict__ rowslot,
    float* __restrict__ wslot, unsigned short* __restrict__ gf)
{
    int s = blockIdx.x;
    int e = 0;
#pragma unroll
    for (int i = 0; i < 8; ++i) if (s >= offs[i + 1]) e = i + 1;
    uint4* dst = (uint4*)&gf[(size_t)s * HH + threadIdx.x * 8];
    bool pad = (e >= 8) || ((s - offs[e]) >= cnt[e]);
    if (pad) {
        if (threadIdx.x == 0) { rowslot[s] = 0; wslot[s] = 0.f; }
        *dst = make_uint4(0u, 0u, 0u, 0u);
        return;
    }
    int b = rowslot[s];
    *dst = *(const uint4*)&featsb[(size_t)b * HH + threadIdx.x * 8];
}

// ---------- launch ----------
extern "C" void kernel_launch(void* const* d_in, const int* in_sizes, int n_in,
                              void* d_out, int out_size, void* d_ws, size_t ws_size,
                              hipStream_t stream)
{
    const float* x    = (const float*)d_in[0];
    const float* fw1  = (const float*)d_in[1];
    const float* fb1  = (const float*)d_in[2];
    const float* fw2  = (const float*)d_in[3];
    const float* fb2  = (const float*)d_in[4];
    const float* kw   = (const float*)d_in[5];
    const float* kb   = (const float*)d_in[6];
    const float* keys = (const float*)d_in[7];
    const float* ew1  = (const float*)d_in[8];
    const float* eb1  = (const float*)d_in[9];
    const float* ew2  = (const float*)d_in[10];
    const float* eb2  = (const float*)d_in[11];
    const float* ew3  = (const float*)d_in[12];
    const float* eb3  = (const float*)d_in[13];

    char* W = (char*)d_ws;
    unsigned short* x_hi  = (unsigned short*)(W + OFF_XHI);
    unsigned short* x_lo  = (unsigned short*)(W + OFF_XLO);
    unsigned short* w1th  = (unsigned short*)(W + OFF_W1TH);
    unsigned short* w1tl  = (unsigned short*)(W + OFF_W1TL);
    unsigned short* w2t   = (unsigned short*)(W + OFF_W2T);
    unsigned short* hph   = (unsigned short*)(W + OFF_HPH);
    unsigned short* hpl   = (unsigned short*)(W + OFF_HPL);
    float*          m2    = (float*)(W + OFF_M2);
    float*          b2    = (float*)(W + OFF_B2);
    unsigned short* featsb= (unsigned short*)(W + OFF_FEATS);
    float*          pkbuf = (float*)(W + OFF_PK);
    unsigned short* gf    = (unsigned short*)(W + OFF_GF);
    unsigned short* h1    = (unsigned short*)(W + OFF_H1);
    unsigned short* h2    = (unsigned short*)(W + OFF_H2);
    unsigned short* ew1t  = (unsigned short*)(W + OFF_EW1T);
    unsigned short* ew2t  = (unsigned short*)(W + OFF_EW2T);
    unsigned short* ew3t  = (unsigned short*)(W + OFF_EW3T);
    float*          wslot = (float*)(W + OFF_WSLOT);
    int*            rowsl = (int*)(W + OFF_ROWSL);
    int*            top_e = (int*)(W + OFF_TOPE);
    float*          top_w = (float*)(W + OFF_TOPW);
    int*            cnt   = (int*)(W + OFF_CNT);
    int*            cnt2  = cnt + 8;
    int*            offs  = cnt + 16;

    float* outF = (float*)d_out;
    float* outW = outF + 8192000;
    float* outT = outF + 8257536;
    float* outS = outF + 8273920;

    hipMemsetAsync(d_out, 0, (size_t)out_size * sizeof(float), stream);
    hipMemsetAsync(W + OFF_CNT, 0, 256, stream);

    // conversions / transposes (ws is re-poisoned every call; must redo each launch)
    k_split_convert<<<dim3((BB * DD) / 1024), 256, 0, stream>>>(x, x_hi, x_lo, BB * DD);
    k_transpose<true ><<<dim3(HH / 32, DD / 32, 1), 256, 0, stream>>>(fw1, w1th, w1tl, DD, HH, HH);
    k_transpose<false><<<dim3(HH / 32, HH / 32, 1), 256, 0, stream>>>(fw2, w2t, nullptr, HH, HH, HH);
    k_transpose<false><<<dim3(HH / 32, HH / 32, EE), 256, 0, stream>>>(ew1, ew1t, nullptr, HH, HH, HH);
    k_transpose<false><<<dim3(HM / 32, HH / 32, EE), 256, 0, stream>>>(ew2, ew2t, nullptr, HH, HM, HM);
    k_transpose<false><<<dim3(CP / 32, HM / 32, EE), 256, 0, stream>>>(ew3, ew3t, nullptr, HM, CC, CP);

    // features
    k_l1<<<dim3(BB / 128, HH / 128), 256, 0, stream>>>(x_hi, x_lo, w1th, w1tl, fb1, hph, hpl);
    k_pk<false><<<dim3(HH / 64), 256, 0, stream>>>(fw2, nullptr, nullptr, kw, nullptr, m2, HH);
    k_bias2<<<1, 128, 0, stream>>>(fb2, kw, kb, b2);
    k_l2<<<dim3(BB / 128, HH / 128), 256, 0, stream>>>(hph, w2t, fb2, featsb);
    k_pk<true ><<<dim3(BB / 64), 256, 0, stream>>>(nullptr, hph, hpl, m2, b2, pkbuf, HH);

    // routing
    k_route<<<dim3(BB), 64, 0, stream>>>(pkbuf, keys, outW, outT, outS, top_e, top_w, cnt);
    k_offs<<<1, 1, 0, stream>>>(cnt, offs);
    k_scatter<<<dim3(BB / 256), 256, 0, stream>>>(top_e, top_w, offs, cnt2, rowsl, wslot);
    k_gather<<<dim3(CAP), 256, 0, stream>>>(featsb, offs, cnt, rowsl, wslot, gf);

    // experts (top-2 only)
    k_le<<<dim3(NT_CAP, HH / 128), 256, 0, stream>>>(gf, ew1t, eb1, h1, offs, HH, HH);
    k_le<<<dim3(NT_CAP, HM / 128), 256, 0, stream>>>(h1, ew2t, eb2, h2, offs, HM, HH);
    k_final<<<dim3(NT_CAP, CP / 128), 256, 0, stream>>>(h2, ew3t, eb3, outF, offs, rowsl, wslot);
}

// Round 2
// 1512.695 us; speedup vs baseline: 1.3764x; 1.3764x over previous
//
#include <hip/hip_runtime.h>

// ---------- types / helpers ----------
typedef __attribute__((ext_vector_type(8))) short short8;   // 8 x bf16 bits
typedef __attribute__((ext_vector_type(4))) float float4v;
typedef __attribute__((ext_vector_type(4))) unsigned short u16x4;

__device__ __forceinline__ float bf2f(unsigned short u) {
    union { unsigned int i; float f; } v; v.i = ((unsigned int)u) << 16; return v.f;
}
__device__ __forceinline__ unsigned short f2bf(float f) {   // round-to-nearest-even
    union { float f; unsigned int u; } v; v.f = f;
    unsigned int u = v.u;
    return (unsigned short)((u + 0x7fffu + ((u >> 16) & 1u)) >> 16);
}
__device__ __forceinline__ void load_lds16(const void* g, void* l) {
    __builtin_amdgcn_global_load_lds((const __attribute__((address_space(1))) void*)g,
                                     (__attribute__((address_space(3))) void*)l, 16, 0, 0);
}
__device__ __forceinline__ float wred(float v) {
#pragma unroll
    for (int o = 32; o > 0; o >>= 1) v += __shfl_down(v, o);
    return __shfl(v, 0);
}

// ---------- problem dims ----------
#define BB 8192
#define DD 1024
#define HH 2048
#define HM 1024
#define CC 1000
#define CP 1024
#define EE 8
#define CAP 17408           // 136 row tiles of 128
#define NT_CAP 136

// ---------- ws layout (bytes) ----------
#define OFF_XHI   0ull
#define OFF_XLO   16777216ull
#define OFF_W1TH  33554432ull
#define OFF_W1TL  37748736ull
#define OFF_W2T   41943040ull
#define OFF_HPH   50331648ull   // ends 83886080
#define OFF_GF    0ull          // alias: x_hi/pkp (dead by gather time)
#define OFF_HPL   83886080ull   // ends 117440512
#define OFF_M2    117440512ull  // m2th (0.5MB) + m2tl (0.5MB)
#define OFF_B2    118489088ull
#define OFF_FEATS 118490112ull  // bf16 feats, ends 152044544
#define OFF_PK    152044544ull  // ends 156238848 (kwt hi/lo early, pkbuf late)
#define OFF_H1    83886080ull   // alias: hpl region is NOT h1! (see below)
#define OFF_EW1T  156238848ull  // ends 223347712
#define OFF_H2    156238848ull  // alias ew1T (dead after expert L1)
#define OFF_EW2T  223347712ull
#define OFF_EW3T  256902144ull
#define OFF_WSLOT 273679360ull
#define OFF_ROWSL 273748992ull
#define OFF_TOPE  273818624ull
#define OFF_TOPW  273884160ull
#define OFF_CNT   273949696ull
// new aliases
#define OFF_FW2H  OFF_HPH                  // 8.4MB, dead before l1 writes hph
#define OFF_FW2L  (OFF_HPH + 8388608ull)
#define OFF_KWTH  OFF_PK                   // 0.5MB, dead before pkred writes pkbuf
#define OFF_KWTL  (OFF_PK + 524288ull)
#define OFF_M2P   OFF_FEATS                // 8MB partials, dead before l2 writes feats
#define OFF_PKP   0ull                     // 16.8MB partials, after l1, dead before gather

// ---------- conversion kernels ----------
__global__ __launch_bounds__(256) void k_split_convert(const float* __restrict__ in,
    unsigned short* __restrict__ hi, unsigned short* __restrict__ lo, int n)
{
    int i = (blockIdx.x * 256 + threadIdx.x) * 4;
    if (i >= n) return;
    float4 v = *(const float4*)(in + i);
    unsigned short h0 = f2bf(v.x), h1 = f2bf(v.y), h2 = f2bf(v.z), h3 = f2bf(v.w);
    u16x4 hv = {h0, h1, h2, h3};
    u16x4 lv = {f2bf(v.x - bf2f(h0)), f2bf(v.y - bf2f(h1)),
                f2bf(v.z - bf2f(h2)), f2bf(v.w - bf2f(h3))};
    *(u16x4*)(hi + i) = hv;
    *(u16x4*)(lo + i) = lv;
}

// out[b][n][k] = in[b][k][n]  (bf16, zero-pad n >= N up to Npad)
template<bool SPLIT>
__global__ __launch_bounds__(256) void k_transpose(const float* __restrict__ in,
    unsigned short* __restrict__ hi, unsigned short* __restrict__ lo, int K, int N, int Npad)
{
    __shared__ float tile[32][33];
    const float* src = in + (size_t)blockIdx.z * K * N;
    int n0 = blockIdx.x * 32, k0 = blockIdx.y * 32;
    int tx = threadIdx.x & 31, ty = threadIdx.x >> 5;
#pragma unroll
    for (int r = ty; r < 32; r += 8) {
        int n = n0 + tx;
        tile[r][tx] = (n < N) ? src[(size_t)(k0 + r) * N + n] : 0.f;
    }
    __syncthreads();
    size_t ob = (size_t)blockIdx.z * Npad * K;
#pragma unroll
    for (int r = ty; r < 32; r += 8) {
        float v = tile[tx][r];
        size_t o = ob + (size_t)(n0 + r) * K + k0 + tx;
        unsigned short h = f2bf(v);
        hi[o] = h;
        if (SPLIT) lo[o] = f2bf(v - bf2f(h));
    }
}

// ---------- bf16 MFMA GEMM core: C[128,128] tile of A[M,K] @ Bt[N,K]^T ----------
__device__ __forceinline__ void gemm_core(const unsigned short* __restrict__ A,
    const unsigned short* __restrict__ Bt, int K, int row0, int col0,
    unsigned short* As, unsigned short* Bs, float4v (&acc)[4][4])
{
    const int t = threadIdx.x, lane = t & 63, w = t >> 6;
    const int lrow = lane & 15, quad = lane >> 4;
    const int swz = (quad ^ ((lrow >> 1) & 3)) * 8;
    const int wr = (w & 1) * 64, wc = (w >> 1) * 64;
    for (int k0 = 0; k0 < K; k0 += 32) {
#pragma unroll
        for (int p = 0; p < 2; ++p) {
            int c = p * 256 + t;
            int r = c >> 2, q = (c & 3) ^ ((r >> 1) & 3);
            int lo_ = (p * 256 + w * 64) * 8;               // wave-uniform LDS dest
            load_lds16(A + (size_t)(row0 + r) * K + k0 + q * 8, As + lo_);
            load_lds16(Bt + (size_t)(col0 + r) * K + k0 + q * 8, Bs + lo_);
        }
        __syncthreads();
        short8 af[4], bfr[4];
#pragma unroll
        for (int i = 0; i < 4; ++i) af[i]  = *(const short8*)(As + (wr + i * 16 + lrow) * 32 + swz);
#pragma unroll
        for (int j = 0; j < 4; ++j) bfr[j] = *(const short8*)(Bs + (wc + j * 16 + lrow) * 32 + swz);
#pragma unroll
        for (int i = 0; i < 4; ++i)
#pragma unroll
            for (int j = 0; j < 4; ++j)
                acc[i][j] = __builtin_amdgcn_mfma_f32_16x16x32_bf16(af[i], bfr[j], acc[i][j], 0, 0, 0);
        __syncthreads();
    }
}

// ---------- layer 1: split (bf16x2) GEMM, relu, split-store ----------
__global__ __launch_bounds__(256, 2) void k_l1(
    const unsigned short* __restrict__ xh, const unsigned short* __restrict__ xl,
    const unsigned short* __restrict__ wh, const unsigned short* __restrict__ wl,
    const float* __restrict__ bias, unsigned short* __restrict__ oh, unsigned short* __restrict__ ol)
{
    __shared__ __align__(16) unsigned short Ash[4096], Asl[4096], Bsh[4096], Bsl[4096];
    const int K = DD, N = HH;
    const int row0 = blockIdx.x * 128, col0 = blockIdx.y * 128;
    const int t = threadIdx.x, lane = t & 63, w = t >> 6;
    const int lrow = lane & 15, quad = lane >> 4;
    const int swz = (quad ^ ((lrow >> 1) & 3)) * 8;
    const int wr = (w & 1) * 64, wc = (w >> 1) * 64;
    float4v acc[4][4] = {};
    for (int k0 = 0; k0 < K; k0 += 32) {
#pragma unroll
        for (int p = 0; p < 2; ++p) {
            int c = p * 256 + t;
            int r = c >> 2, q = (c & 3) ^ ((r >> 1) & 3);
            size_t ga = (size_t)(row0 + r) * K + k0 + q * 8;
            size_t gb = (size_t)(col0 + r) * K + k0 + q * 8;
            int lo_ = (p * 256 + w * 64) * 8;
            load_lds16(xh + ga, Ash + lo_);
            load_lds16(xl + ga, Asl + lo_);
            load_lds16(wh + gb, Bsh + lo_);
            load_lds16(wl + gb, Bsl + lo_);
        }
        __syncthreads();
        short8 ah[4], al[4], bh[4], bl[4];
#pragma unroll
        for (int i = 0; i < 4; ++i) {
            int o = (wr + i * 16 + lrow) * 32 + swz;
            ah[i] = *(const short8*)(Ash + o);
            al[i] = *(const short8*)(Asl + o);
        }
#pragma unroll
        for (int j = 0; j < 4; ++j) {
            int o = (wc + j * 16 + lrow) * 32 + swz;
            bh[j] = *(const short8*)(Bsh + o);
            bl[j] = *(const short8*)(Bsl + o);
        }
#pragma unroll
        for (int i = 0; i < 4; ++i)
#pragma unroll
            for (int j = 0; j < 4; ++j) {
                float4v a0 = __builtin_amdgcn_mfma_f32_16x16x32_bf16(al[i], bh[j], acc[i][j], 0, 0, 0);
                a0 = __builtin_amdgcn_mfma_f32_16x16x32_bf16(ah[i], bl[j], a0, 0, 0, 0);
                acc[i][j] = __builtin_amdgcn_mfma_f32_16x16x32_bf16(ah[i], bh[j], a0, 0, 0, 0);
            }
        __syncthreads();
    }
#pragma unroll
    for (int i = 0; i < 4; ++i)
#pragma unroll
        for (int r = 0; r < 4; ++r) {
            int row = row0 + wr + i * 16 + quad * 4 + r;
            size_t base = (size_t)row * N;
#pragma unroll
            for (int j = 0; j < 4; ++j) {
                int col = col0 + wc + j * 16 + lrow;
                float v = fmaxf(acc[i][j][r] + bias[col], 0.f);
                unsigned short h = f2bf(v);
                oh[base + col] = h;
                ol[base + col] = f2bf(v - bf2f(h));
            }
        }
}

// ---------- generic 3-term split GEMM, N=128, split-K, fp32 partial out ----------
// out slice: out + blockIdx.y * (gridDim.x*128) * 128 ; k-range [blockIdx.y*klen, +klen)
__global__ __launch_bounds__(256, 2) void k_split3(
    const unsigned short* __restrict__ ah_, const unsigned short* __restrict__ al_,
    const unsigned short* __restrict__ bh_, const unsigned short* __restrict__ bl_,
    float* __restrict__ out, int K, int klen)
{
    __shared__ __align__(16) unsigned short Ash[4096], Asl[4096], Bsh[4096], Bsl[4096];
    const int row0 = blockIdx.x * 128;
    const int kb = blockIdx.y * klen;
    out += (size_t)blockIdx.y * gridDim.x * 128 * 128;
    const int t = threadIdx.x, lane = t & 63, w = t >> 6;
    const int lrow = lane & 15, quad = lane >> 4;
    const int swz = (quad ^ ((lrow >> 1) & 3)) * 8;
    const int wr = (w & 1) * 64, wc = (w >> 1) * 64;
    float4v acc[4][4] = {};
    for (int k0 = kb; k0 < kb + klen; k0 += 32) {
#pragma unroll
        for (int p = 0; p < 2; ++p) {
            int c = p * 256 + t;
            int r = c >> 2, q = (c & 3) ^ ((r >> 1) & 3);
            size_t ga = (size_t)(row0 + r) * K + k0 + q * 8;
            size_t gb = (size_t)r * K + k0 + q * 8;           // B has exactly 128 rows
            int lo_ = (p * 256 + w * 64) * 8;
            load_lds16(ah_ + ga, Ash + lo_);
            load_lds16(al_ + ga, Asl + lo_);
            load_lds16(bh_ + gb, Bsh + lo_);
            load_lds16(bl_ + gb, Bsl + lo_);
        }
        __syncthreads();
        short8 ah[4], al[4], bh[4], bl[4];
#pragma unroll
        for (int i = 0; i < 4; ++i) {
            int o = (wr + i * 16 + lrow) * 32 + swz;
            ah[i] = *(const short8*)(Ash + o);
            al[i] = *(const short8*)(Asl + o);
        }
#pragma unroll
        for (int j = 0; j < 4; ++j) {
            int o = (wc + j * 16 + lrow) * 32 + swz;
            bh[j] = *(const short8*)(Bsh + o);
            bl[j] = *(const short8*)(Bsl + o);
        }
#pragma unroll
        for (int i = 0; i < 4; ++i)
#pragma unroll
            for (int j = 0; j < 4; ++j) {
                float4v a0 = __builtin_amdgcn_mfma_f32_16x16x32_bf16(al[i], bh[j], acc[i][j], 0, 0, 0);
                a0 = __builtin_amdgcn_mfma_f32_16x16x32_bf16(ah[i], bl[j], a0, 0, 0, 0);
                acc[i][j] = __builtin_amdgcn_mfma_f32_16x16x32_bf16(ah[i], bh[j], a0, 0, 0, 0);
            }
        __syncthreads();
    }
#pragma unroll
    for (int i = 0; i < 4; ++i)
#pragma unroll
        for (int r = 0; r < 4; ++r) {
            int row = row0 + wr + i * 16 + quad * 4 + r;
            size_t base = (size_t)row * 128;
#pragma unroll
            for (int j = 0; j < 4; ++j) {
                int col = wc + j * 16 + lrow;
                out[base + col] = acc[i][j][r];
            }
        }
}

// ---------- M2 reduce: sum 8 partials, transpose, split to bf16 hi/lo ----------
__global__ __launch_bounds__(256) void k_m2red(const float* __restrict__ p,
    unsigned short* __restrict__ th, unsigned short* __restrict__ tl)
{
    __shared__ float tile[32][33];
    const int h0 = blockIdx.x * 32, c0 = blockIdx.y * 32;
    const int t = threadIdx.x;
    {
        int r = t >> 3, cq = (t & 7) * 4;
        size_t base = (size_t)(h0 + r) * 128 + c0 + cq;
        float4 s = *(const float4*)(p + base);
#pragma unroll
        for (int ks = 1; ks < 8; ++ks) {
            float4 v = *(const float4*)(p + (size_t)ks * HH * 128 + base);
            s.x += v.x; s.y += v.y; s.z += v.z; s.w += v.w;
        }
        tile[r][cq] = s.x; tile[r][cq + 1] = s.y; tile[r][cq + 2] = s.z; tile[r][cq + 3] = s.w;
    }
    __syncthreads();
    {
        int cr = t >> 3, hq = (t & 7) * 4;
        u16x4 hv, lv;
#pragma unroll
        for (int i = 0; i < 4; ++i) {
            float v = tile[hq + i][cr];
            unsigned short h = f2bf(v);
            hv[i] = h; lv[i] = f2bf(v - bf2f(h));
        }
        size_t o = (size_t)(c0 + cr) * HH + h0 + hq;
        *(u16x4*)(th + o) = hv;
        *(u16x4*)(tl + o) = lv;
    }
}

// ---------- pk reduce: sum 4 partials + bias ----------
__global__ __launch_bounds__(256) void k_pkred(const float* __restrict__ p,
    const float* __restrict__ b2, float* __restrict__ out)
{
    int idx = blockIdx.x * 256 + threadIdx.x;
    const size_t S = (size_t)BB * 128;
    out[idx] = p[idx] + p[idx + S] + p[idx + 2 * S] + p[idx + 3 * S] + b2[idx & 127];
}

// ---------- layer 2: single bf16 GEMM -> feats bf16 (no relu) ----------
__global__ __launch_bounds__(256, 2) void k_l2(const unsigned short* __restrict__ A,
    const unsigned short* __restrict__ Bt, const float* __restrict__ bias,
    unsigned short* __restrict__ outb)
{
    __shared__ __align__(16) unsigned short As[4096], Bs[4096];
    const int K = HH, N = HH;
    const int row0 = blockIdx.x * 128, col0 = blockIdx.y * 128;
    float4v acc[4][4] = {};
    gemm_core(A, Bt, K, row0, col0, As, Bs, acc);
    const int lane = threadIdx.x & 63, w = threadIdx.x >> 6;
    const int lrow = lane & 15, quad = lane >> 4;
    const int wr = (w & 1) * 64, wc = (w >> 1) * 64;
#pragma unroll
    for (int i = 0; i < 4; ++i)
#pragma unroll
        for (int r = 0; r < 4; ++r) {
            int row = row0 + wr + i * 16 + quad * 4 + r;
            size_t base = (size_t)row * N;
#pragma unroll
            for (int j = 0; j < 4; ++j) {
                int col = col0 + wc + j * 16 + lrow;
                outb[base + col] = f2bf(acc[i][j][r] + bias[col]);
            }
        }
}

// ---------- expert GEMM (relu, bf16 out), expert chosen per 128-row tile ----------
__global__ __launch_bounds__(256, 2) void k_le(const unsigned short* __restrict__ A,
    const unsigned short* __restrict__ WT, const float* __restrict__ bias,
    unsigned short* __restrict__ out, const int* __restrict__ offs, int N, int K)
{
    __shared__ __align__(16) unsigned short As[4096], Bs[4096];
    const int row0 = blockIdx.x * 128;
    if (row0 >= offs[8]) return;
    int e = 0;
#pragma unroll
    for (int i = 1; i < 8; ++i) if (offs[i] <= row0) e = i;
    const unsigned short* Bt = WT + (size_t)e * N * K;
    const float* bs = bias + (size_t)e * N;
    const int col0 = blockIdx.y * 128;
    float4v acc[4][4] = {};
    gemm_core(A, Bt, K, row0, col0, As, Bs, acc);
    const int lane = threadIdx.x & 63, w = threadIdx.x >> 6;
    const int lrow = lane & 15, quad = lane >> 4;
    const int wr = (w & 1) * 64, wc = (w >> 1) * 64;
#pragma unroll
    for (int i = 0; i < 4; ++i)
#pragma unroll
        for (int r = 0; r < 4; ++r) {
            int row = row0 + wr + i * 16 + quad * 4 + r;
            size_t base = (size_t)row * N;
#pragma unroll
            for (int j = 0; j < 4; ++j) {
                int col = col0 + wc + j * 16 + lrow;
                out[base + col] = f2bf(fmaxf(acc[i][j][r] + bs[col], 0.f));
            }
        }
}

// ---------- final expert GEMM: weighted atomic accumulate into final ----------
__global__ __launch_bounds__(256, 2) void k_final(const unsigned short* __restrict__ A,
    const unsigned short* __restrict__ WT, const float* __restrict__ bias,
    float* __restrict__ outF, const int* __restrict__ offs,
    const int* __restrict__ rowslot, const float* __restrict__ wslot)
{
    __shared__ __align__(16) unsigned short As[4096], Bs[4096];
    const int N = CP, K = HM;
    const int row0 = blockIdx.x * 128;
    if (row0 >= offs[8]) return;
    int e = 0;
#pragma unroll
    for (int i = 1; i < 8; ++i) if (offs[i] <= row0) e = i;
    const unsigned short* Bt = WT + (size_t)e * N * K;
    const float* bs = bias + (size_t)e * CC;
    const int col0 = blockIdx.y * 128;
    float4v acc[4][4] = {};
    gemm_core(A, Bt, K, row0, col0, As, Bs, acc);
    const int lane = threadIdx.x & 63, w = threadIdx.x >> 6;
    const int lrow = lane & 15, quad = lane >> 4;
    const int wr = (w & 1) * 64, wc = (w >> 1) * 64;
#pragma unroll
    for (int i = 0; i < 4; ++i)
#pragma unroll
        for (int r = 0; r < 4; ++r) {
            int row = row0 + wr + i * 16 + quad * 4 + r;
            float wv = wslot[row];
            if (wv != 0.f) {
                float* frow = outF + (size_t)rowslot[row] * CC;
#pragma unroll
                for (int j = 0; j < 4; ++j) {
                    int col = col0 + wc + j * 16 + lrow;
                    if (col < CC) atomicAdd(frow + col, wv * (acc[i][j][r] + bs[col]));
                }
            }
        }
}

// ---------- b2[c] = sum_j fb2[j]*kw[j,c] + kb[c] ----------
__global__ __launch_bounds__(64) void k_bias2(const float* __restrict__ fb2,
    const float* __restrict__ kw, const float* __restrict__ kb, float* __restrict__ b2)
{
    int c = blockIdx.x, lane = threadIdx.x;
    float s = 0.f;
    for (int j = lane; j < HH; j += 64) s += fb2[j] * kw[(size_t)j * 128 + c];
    s = wred(s);
    if (lane == 0) b2[c] = s + kb[c];
}

// ---------- routing ----------
__global__ __launch_bounds__(64) void k_route(const float* __restrict__ pk,
    const float* __restrict__ keys, float* __restrict__ wout, float* __restrict__ tout,
    float* __restrict__ simout, int* __restrict__ top_e, float* __restrict__ top_w,
    int* __restrict__ cnt)
{
    int b = blockIdx.x, lane = threadIdx.x;
    float2 v = *(const float2*)&pk[(size_t)b * 128 + lane * 2];
    float inv = 1.f / fmaxf(sqrtf(wred(v.x * v.x + v.y * v.y)), 1e-12f);
    float sims[8];
#pragma unroll
    for (int e = 0; e < 8; ++e) {
        float2 kv = *(const float2*)&keys[e * 128 + lane * 2];
        float kinv = 1.f / fmaxf(sqrtf(wred(kv.x * kv.x + kv.y * kv.y)), 1e-12f);
        float d = wred(v.x * kv.x + v.y * kv.y);
        sims[e] = d * inv * kinv;
    }
    if (lane == 0) {
        int i1 = 0; float v1 = sims[0];
#pragma unroll
        for (int e = 1; e < 8; ++e) if (sims[e] > v1) { v1 = sims[e]; i1 = e; }
        int i2 = -1; float v2 = -1e30f;
#pragma unroll
        for (int e = 0; e < 8; ++e) if (e != i1 && sims[e] > v2) { v2 = sims[e]; i2 = e; }
        float e2 = expf(v2 - v1);
        float w1 = 1.f / (1.f + e2), w2 = e2 / (1.f + e2);
#pragma unroll
        for (int e = 0; e < 8; ++e) simout[(size_t)b * 8 + e] = sims[e];
        wout[(size_t)b * 8 + i1] = w1;
        wout[(size_t)b * 8 + i2] = w2;
        tout[(size_t)b * 2] = (float)i1; tout[(size_t)b * 2 + 1] = (float)i2;
        top_e[b * 2] = i1; top_e[b * 2 + 1] = i2;
        top_w[b * 2] = w1; top_w[b * 2 + 1] = w2;
        atomicAdd(&cnt[i1], 1); atomicAdd(&cnt[i2], 1);
    }
}

__global__ void k_offs(const int* __restrict__ cnt, int* __restrict__ offs)
{
    if (threadIdx.x == 0) {
        int o = 0;
        for (int e = 0; e < 8; ++e) { offs[e] = o; o += ((cnt[e] + 127) >> 7) << 7; }
        offs[8] = o;
    }
}

__global__ __launch_bounds__(256) void k_scatter(const int* __restrict__ top_e,
    const float* __restrict__ top_w, const int* __restrict__ offs, int* __restrict__ cnt2,
    int* __restrict__ rowslot, float* __restrict__ wslot)
{
    int b = blockIdx.x * 256 + threadIdx.x;
    if (b >= BB) return;
#pragma unroll
    for (int j = 0; j < 2; ++j) {
        int e = top_e[b * 2 + j];
        int idx = atomicAdd(&cnt2[e], 1);
        int s = offs[e] + idx;
        rowslot[s] = b;
        wslot[s] = top_w[b * 2 + j];
    }
}

__global__ __launch_bounds__(256) void k_gather(const unsigned short* __restrict__ featsb,
    const int* __restrict__ offs, const int* __restrict__ cnt, int* __restrict__ rowslot,
    float* __restrict__ wslot, unsigned short* __restrict__ gf)
{
    int s = blockIdx.x;
    int e = 0;
#pragma unroll
    for (int i = 0; i < 8; ++i) if (s >= offs[i + 1]) e = i + 1;
    uint4* dst = (uint4*)&gf[(size_t)s * HH + threadIdx.x * 8];
    bool pad = (e >= 8) || ((s - offs[e]) >= cnt[e]);
    if (pad) {
        if (threadIdx.x == 0) { rowslot[s] = 0; wslot[s] = 0.f; }
        *dst = make_uint4(0u, 0u, 0u, 0u);
        return;
    }
    int b = rowslot[s];
    *dst = *(const uint4*)&featsb[(size_t)b * HH + threadIdx.x * 8];
}

// ---------- launch ----------
extern "C" void kernel_launch(void* const* d_in, const int* in_sizes, int n_in,
                              void* d_out, int out_size, void* d_ws, size_t ws_size,
                              hipStream_t stream)
{
    const float* x    = (const float*)d_in[0];
    const float* fw1  = (const float*)d_in[1];
    const float* fb1  = (const float*)d_in[2];
    const float* fw2  = (const float*)d_in[3];
    const float* fb2  = (const float*)d_in[4];
    const float* kw   = (const float*)d_in[5];
    const float* kb   = (const float*)d_in[6];
    const float* keys = (const float*)d_in[7];
    const float* ew1  = (const float*)d_in[8];
    const float* eb1  = (const float*)d_in[9];
    const float* ew2  = (const float*)d_in[10];
    const float* eb2  = (const float*)d_in[11];
    const float* ew3  = (const float*)d_in[12];
    const float* eb3  = (const float*)d_in[13];

    char* W = (char*)d_ws;
    unsigned short* x_hi  = (unsigned short*)(W + OFF_XHI);
    unsigned short* x_lo  = (unsigned short*)(W + OFF_XLO);
    unsigned short* w1th  = (unsigned short*)(W + OFF_W1TH);
    unsigned short* w1tl  = (unsigned short*)(W + OFF_W1TL);
    unsigned short* w2t   = (unsigned short*)(W + OFF_W2T);
    unsigned short* hph   = (unsigned short*)(W + OFF_HPH);
    unsigned short* hpl   = (unsigned short*)(W + OFF_HPL);
    unsigned short* fw2h  = (unsigned short*)(W + OFF_FW2H);
    unsigned short* fw2l  = (unsigned short*)(W + OFF_FW2L);
    unsigned short* kwth  = (unsigned short*)(W + OFF_KWTH);
    unsigned short* kwtl  = (unsigned short*)(W + OFF_KWTL);
    unsigned short* m2th  = (unsigned short*)(W + OFF_M2);
    unsigned short* m2tl  = (unsigned short*)(W + OFF_M2 + 524288ull);
    float*          m2p   = (float*)(W + OFF_M2P);
    float*          pkp   = (float*)(W + OFF_PKP);
    float*          b2    = (float*)(W + OFF_B2);
    unsigned short* featsb= (unsigned short*)(W + OFF_FEATS);
    float*          pkbuf = (float*)(W + OFF_PK);
    unsigned short* gf    = (unsigned short*)(W + OFF_GF);
    unsigned short* h1    = (unsigned short*)(W + OFF_H1);
    unsigned short* h2    = (unsigned short*)(W + OFF_H2);
    unsigned short* ew1t  = (unsigned short*)(W + OFF_EW1T);
    unsigned short* ew2t  = (unsigned short*)(W + OFF_EW2T);
    unsigned short* ew3t  = (unsigned short*)(W + OFF_EW3T);
    float*          wslot = (float*)(W + OFF_WSLOT);
    int*            rowsl = (int*)(W + OFF_ROWSL);
    int*            top_e = (int*)(W + OFF_TOPE);
    float*          top_w = (float*)(W + OFF_TOPW);
    int*            cnt   = (int*)(W + OFF_CNT);
    int*            cnt2  = cnt + 8;
    int*            offs  = cnt + 16;

    float* outF = (float*)d_out;
    float* outW = outF + 8192000;
    float* outT = outF + 8257536;
    float* outS = outF + 8273920;

    hipMemsetAsync(d_out, 0, (size_t)out_size * sizeof(float), stream);
    hipMemsetAsync(W + OFF_CNT, 0, 256, stream);

    // conversions / transposes (ws is re-poisoned every call; must redo each launch)
    k_split_convert<<<dim3((BB * DD) / 1024), 256, 0, stream>>>(x, x_hi, x_lo, BB * DD);
    k_split_convert<<<dim3((HH * HH) / 1024), 256, 0, stream>>>(fw2, fw2h, fw2l, HH * HH);
    k_transpose<true ><<<dim3(128 / 32, HH / 32, 1), 256, 0, stream>>>(kw, kwth, kwtl, HH, 128, 128);
    k_transpose<true ><<<dim3(HH / 32, DD / 32, 1), 256, 0, stream>>>(fw1, w1th, w1tl, DD, HH, HH);
    k_transpose<false><<<dim3(HH / 32, HH / 32, 1), 256, 0, stream>>>(fw2, w2t, nullptr, HH, HH, HH);
    k_transpose<false><<<dim3(HH / 32, HH / 32, EE), 256, 0, stream>>>(ew1, ew1t, nullptr, HH, HH, HH);
    k_transpose<false><<<dim3(HM / 32, HH / 32, EE), 256, 0, stream>>>(ew2, ew2t, nullptr, HH, HM, HM);
    k_transpose<false><<<dim3(CP / 32, HM / 32, EE), 256, 0, stream>>>(ew3, ew3t, nullptr, HM, CC, CP);

    // M2 = fw2 @ kw  (3-term split MFMA, split-K=8, then reduce+transpose+split)
    k_split3<<<dim3(HH / 128, 8), 256, 0, stream>>>(fw2h, fw2l, kwth, kwtl, m2p, HH, HH / 8);
    k_m2red<<<dim3(HH / 32, 128 / 32), 256, 0, stream>>>(m2p, m2th, m2tl);
    k_bias2<<<dim3(128), 64, 0, stream>>>(fb2, kw, kb, b2);

    // features
    k_l1<<<dim3(BB / 128, HH / 128), 256, 0, stream>>>(x_hi, x_lo, w1th, w1tl, fb1, hph, hpl);
    k_l2<<<dim3(BB / 128, HH / 128), 256, 0, stream>>>(hph, w2t, fb2, featsb);

    // pk = hpre @ M2 (3-term split MFMA, split-K=4, then reduce + bias)
    k_split3<<<dim3(BB / 128, 4), 256, 0, stream>>>(hph, hpl, m2th, m2tl, pkp, HH, HH / 4);
    k_pkred<<<dim3((BB * 128) / 256), 256, 0, stream>>>(pkp, b2, pkbuf);

    // routing
    k_route<<<dim3(BB), 64, 0, stream>>>(pkbuf, keys, outW, outT, outS, top_e, top_w, cnt);
    k_offs<<<1, 1, 0, stream>>>(cnt, offs);
    k_scatter<<<dim3(BB / 256), 256, 0, stream>>>(top_e, top_w, offs, cnt2, rowsl, wslot);
    k_gather<<<dim3(CAP), 256, 0, stream>>>(featsb, offs, cnt, rowsl, wslot, gf);

    // experts (top-2 only)
    k_le<<<dim3(NT_CAP, HH / 128), 256, 0, stream>>>(gf, ew1t, eb1, h1, offs, HH, HH);
    k_le<<<dim3(NT_CAP, HM / 128), 256, 0, stream>>>(h1, ew2t, eb2, h2, offs, HM, HH);
    k_final<<<dim3(NT_CAP, CP / 128), 256, 0, stream>>>(h2, ew3t, eb3, outF, offs, rowsl, wslot);
}